// Round 12
// baseline (110.607 us; speedup 1.0000x reference)
//
#include <hip/hip_runtime.h>

#define BB 4
#define CC 3
#define HH 512
#define WW 512
#define NS 81              // 9 x 9 shifts
#define IMG (HH * WW)
#define CHW (CC * IMG)
#define STRIP 32           // rows per k_sims block (8 rows per wave)
#define NSTRIP (HH / STRIP)              // 16
#define NBLK (BB * CC * NSTRIP * 9)      // 1728 blocks (one sx each)

// ws layout: double sims[BB][81] at byte 0 (2592 B, zeroed by a memset node).

// constant-index component select (folds after full unroll)
#define C4(v, i) ((i) == 0 ? (v).x : (i) == 1 ? (v).y : (i) == 2 ? (v).z : (v).w)

// sim(b,sx,sy) = sum over c,i,j (both (i,j) and (i+sx,j+sy) in bounds) of
//               x[b,c,i,j] * x_ref[b,c,i+sx,j+sy]
// R12 = R11 body with MAX-MLP: all 32 row-loads (8 rows x 4 aligned float4)
// hoisted to the top as INDIVIDUALLY NAMED float4s (no arrays -- every spill
// incident R6/R7/R9 involved an alloca; named scalars were always clean).
// Branch-free boundary = clamp ref row + 0/1 row mask folded into x (R9
// numerics). launch_bounds(256,2) -> 256-VGPR budget for ~170 live regs.
// Compiler then emits fine-grained vmcnt per row: 28 loads stay in flight
// during each row's 72 FMAs -- ILP latency hiding, the one untried lever
// (VALUBusy 18-26% + 1 TB/s fetch proved latency-bound, not pipe-bound).
__global__ __launch_bounds__(256, 2) void k_sims(const float* __restrict__ xref,
                                                 const float* __restrict__ x,
                                                 double* __restrict__ sims) {
    int bid  = blockIdx.x;
    int sxi  = bid % 9;                  // sx = sxi - 4
    int tmp  = bid / 9;
    int strip = tmp % NSTRIP;
    int bc   = tmp / NSTRIP;
    int b    = bc / CC;
    const float* xp = x    + (size_t)bc * IMG;
    const float* rp = xref + (size_t)bc * IMG;
    int tid  = threadIdx.x;
    int lane = tid & 63;
    int wave = tid >> 6;
    int j0   = lane << 3;                // 8 floats per lane
    int sx   = sxi - 4;
    int ip0  = strip * STRIP + wave * 8;

    float acc[9];
#pragma unroll
    for (int s = 0; s < 9; ++s) acc[s] = 0.f;

    // ---- load phase: 32 independent aligned float4 loads, all in flight ----
#define DECL_ROW(R) float4 xa##R, xb##R, ra##R, rb##R; float m##R;
#define LOAD_ROW(R)                                                           \
    {                                                                         \
        int ip  = ip0 + (R);                                                  \
        int ii  = ip + sx;                                                    \
        m##R    = ((unsigned)ii < HH) ? 1.f : 0.f;                            \
        int iic = ii < 0 ? 0 : (ii > HH - 1 ? HH - 1 : ii);                   \
        const float* xr = xp + ip * WW + j0;                                  \
        const float* rw = rp + iic * WW + j0;                                 \
        xa##R = *(const float4*)(xr);                                         \
        xb##R = *(const float4*)(xr + 4);                                     \
        ra##R = *(const float4*)(rw);                                         \
        rb##R = *(const float4*)(rw + 4);                                     \
    }
    DECL_ROW(0) DECL_ROW(1) DECL_ROW(2) DECL_ROW(3)
    DECL_ROW(4) DECL_ROW(5) DECL_ROW(6) DECL_ROW(7)
    LOAD_ROW(0) LOAD_ROW(1) LOAD_ROW(2) LOAD_ROW(3)
    LOAD_ROW(4) LOAD_ROW(5) LOAD_ROW(6) LOAD_ROW(7)

    // ---- compute phase: per row, halo shuffles + 72 FMAs ----
#define COMP_ROW(R)                                                           \
    {                                                                         \
        float p0 = __shfl_up(rb##R.x, 1, 64);                                 \
        float p1 = __shfl_up(rb##R.y, 1, 64);                                 \
        float p2 = __shfl_up(rb##R.z, 1, 64);                                 \
        float p3 = __shfl_up(rb##R.w, 1, 64);                                 \
        if (lane == 0) { p0 = p1 = p2 = p3 = 0.f; }                           \
        float n0 = __shfl_down(ra##R.x, 1, 64);                               \
        float n1 = __shfl_down(ra##R.y, 1, 64);                               \
        float n2 = __shfl_down(ra##R.z, 1, 64);                               \
        float n3 = __shfl_down(ra##R.w, 1, 64);                               \
        if (lane == 63) { n0 = n1 = n2 = n3 = 0.f; }                          \
        float q0 = xa##R.x * m##R, q1 = xa##R.y * m##R;                       \
        float q2 = xa##R.z * m##R, q3 = xa##R.w * m##R;                       \
        float q4 = xb##R.x * m##R, q5 = xb##R.y * m##R;                       \
        float q6 = xb##R.z * m##R, q7 = xb##R.w * m##R;                       \
        _Pragma("unroll")                                                     \
        for (int syi = 0; syi < 9; ++syi) {                                   \
            _Pragma("unroll")                                                 \
            for (int k = 0; k < 8; ++k) {                                     \
                int i = k + syi;                                              \
                float wv = (i < 4)  ? ((i)==0?p0:(i)==1?p1:(i)==2?p2:p3)      \
                         : (i < 8)  ? C4(ra##R, i - 4)                        \
                         : (i < 12) ? C4(rb##R, i - 8)                        \
                         : ((i)==12?n0:(i)==13?n1:(i)==14?n2:n3);             \
                float xv = (k)==0?q0:(k)==1?q1:(k)==2?q2:(k)==3?q3:           \
                           (k)==4?q4:(k)==5?q5:(k)==6?q6:q7;                  \
                acc[syi] += xv * wv;                                          \
            }                                                                 \
        }                                                                     \
    }
    COMP_ROW(0) COMP_ROW(1) COMP_ROW(2) COMP_ROW(3)
    COMP_ROW(4) COMP_ROW(5) COMP_ROW(6) COMP_ROW(7)
#undef DECL_ROW
#undef LOAD_ROW
#undef COMP_ROW

    // wave reduce (fp32), block combine in LDS, 9 fp64 atomics per block.
    // Numerics: fp32 block partials summed in fp64 (R2-proven); atomic order
    // nondeterminism ~1e-10 vs inter-sim gaps O(100) -> argmax stable.
    __shared__ float part[4][9];
#pragma unroll
    for (int s = 0; s < 9; ++s) {
        float v = acc[s];
        for (int off = 32; off; off >>= 1) v += __shfl_down(v, off, 64);
        if (lane == 0) part[wave][s] = v;
    }
    __syncthreads();
    if (tid < 9) {
        double tot = (double)part[0][tid] + (double)part[1][tid]
                   + (double)part[2][tid] + (double)part[3][tid];
        atomicAdd(&sims[b * NS + sxi * 9 + tid], tot);
    }
}

// Fused argmax + apply. Each block re-derives its batch's argmax from the
// 81 fp64 sims (L2-resident, 648 B) with first-index tie-break, then shifts
// its 2 rows. One designated block per batch also writes the shift tail.
__global__ __launch_bounds__(256) void k_apply(const float* __restrict__ x,
                                               const double* __restrict__ sims,
                                               float* __restrict__ out,
                                               float* __restrict__ outTail) {
    int blk = blockIdx.x;
    int bc  = blk >> 8;                 // 256 blocks per image (512 rows / 2)
    int tid = threadIdx.x;
    int b   = bc / CC;

    __shared__ double vals[NS];
    __shared__ int bestIdx;
    if (tid < NS) vals[tid] = sims[b * NS + tid];
    __syncthreads();
    if (tid < 64) {
        double v = vals[tid];
        int    i = tid;
        if (tid < NS - 64) {
            double v2 = vals[tid + 64];          // higher index: strict > only
            if (v2 > v) { v = v2; i = tid + 64; }
        }
        for (int off = 32; off; off >>= 1) {
            double ov = __shfl_down(v, off, 64);
            int    oi = __shfl_down(i, off, 64);
            if (ov > v || (ov == v && oi < i)) { v = ov; i = oi; }
        }
        if (tid == 0) bestIdx = i;
    }
    __syncthreads();
    int bi = bestIdx;
    int sx = bi / 9 - 4;
    int sy = bi % 9 - 4;
    if (blk == ((b * CC) << 8) && tid == 0) {    // one block per batch
        outTail[b * 2]     = (float)sx;
        outTail[b * 2 + 1] = (float)sy;
    }

    int row = ((blk & 255) << 1) + (tid >> 7);
    int j0  = (tid & 127) << 2;
    int is  = row - sx;
    float4 v = make_float4(0.f, 0.f, 0.f, 0.f);
    if ((unsigned)is < HH) {
        const float* src = x + (size_t)bc * IMG + is * WW;
        int js0 = j0 - sy;
        if (js0 >= 0 && js0 + 3 < WW) {
            v = *(const float4*)(src + js0);   // 4B-aligned dwordx4, exact (R2-R11)
        } else {
            float* vv = (float*)&v;
#pragma unroll
            for (int k = 0; k < 4; ++k) {
                int js = js0 + k;
                if ((unsigned)js < WW) vv[k] = src[js];
            }
        }
    }
    *(float4*)(out + (size_t)bc * IMG + row * WW + j0) = v;
}

extern "C" void kernel_launch(void* const* d_in, const int* in_sizes, int n_in,
                              void* d_out, int out_size, void* d_ws, size_t ws_size,
                              hipStream_t stream) {
    const float* xref = (const float*)d_in[0];
    const float* x    = (const float*)d_in[1];
    float* out = (float*)d_out;

    double* sims = (double*)d_ws;

    hipMemsetAsync(sims, 0, BB * NS * sizeof(double), stream);

    k_sims<<<NBLK, 256, 0, stream>>>(xref, x, sims);

    int applyBlocks = (BB * CC * HH) / 2;   // 3072
    k_apply<<<applyBlocks, 256, 0, stream>>>(x, sims, out, out + (size_t)BB * CHW);
}

// Round 13
// 107.910 us; speedup vs baseline: 1.0250x; 1.0250x over previous
//
#include <hip/hip_runtime.h>

#define BB 4
#define CC 3
#define HH 512
#define WW 512
#define NS 81              // 9 x 9 shifts
#define IMG (HH * WW)
#define CHW (CC * IMG)
#define STRIP 32           // rows per k_sims block (8 rows per wave)
#define NSTRIP (HH / STRIP)              // 16
#define NBLK (BB * CC * NSTRIP * 9)      // 1728 blocks (one sx each)

// ws layout: double sims[BB][81] at byte 0 (2592 B, zeroed by a memset node).

// constant-index component select (folds after full unroll)
#define C4(v, i) ((i) == 0 ? (v).x : (i) == 1 ? (v).y : (i) == 2 ? (v).z : (v).w)

// sim(b,sx,sy) = sum over c,i,j (both (i,j) and (i+sx,j+sy) in bounds) of
//               x[b,c,i,j] * x_ref[b,c,i+sx,j+sy]
// R11 final: best-measured configuration (108.96 us total, absmax 0).
// Seven orthogonal k_sims levers (TLP, reduction cost, alignment, XCD
// swizzle, LDS-DMA staging, graph shape, ILP) all landed at the same
// ~35-40 us plateau -> latency-structured floor for this dispatch size.
__global__ __launch_bounds__(256, 4) void k_sims(const float* __restrict__ xref,
                                                 const float* __restrict__ x,
                                                 double* __restrict__ sims) {
    int bid  = blockIdx.x;
    int sxi  = bid % 9;                  // sx = sxi - 4
    int tmp  = bid / 9;
    int strip = tmp % NSTRIP;
    int bc   = tmp / NSTRIP;
    int b    = bc / CC;
    const float* xp = x    + (size_t)bc * IMG;
    const float* rp = xref + (size_t)bc * IMG;
    int tid  = threadIdx.x;
    int lane = tid & 63;
    int wave = tid >> 6;
    int j0   = lane << 3;                // 8 floats per lane
    int sx   = sxi - 4;
    int ip0  = strip * STRIP + wave * 8;

    float acc[9];
#pragma unroll
    for (int s = 0; s < 9; ++s) acc[s] = 0.f;

#pragma unroll
    for (int rr = 0; rr < 8; ++rr) {
        int ip = ip0 + rr;               // x row (always in bounds)
        int ii = ip + sx;                // ref row (wave-uniform test)
        if ((unsigned)ii >= HH) continue;

        const float* xrow = xp + ip * WW + j0;
        const float* rrow = rp + ii * WW + j0;
        float4 xa = *(const float4*)(xrow);        // x   cols j0   .. j0+3
        float4 xb = *(const float4*)(xrow + 4);    // x   cols j0+4 .. j0+7
        float4 ra = *(const float4*)(rrow);        // ref cols j0   .. j0+3
        float4 rb = *(const float4*)(rrow + 4);    // ref cols j0+4 .. j0+7

        // halo: prev4 = ref cols j0-4..j0-1 (lane-1's rb), next4 = j0+8..j0+11
        float p0 = __shfl_up(rb.x, 1, 64);
        float p1 = __shfl_up(rb.y, 1, 64);
        float p2 = __shfl_up(rb.z, 1, 64);
        float p3 = __shfl_up(rb.w, 1, 64);
        if (lane == 0) { p0 = p1 = p2 = p3 = 0.f; }   // cols < 0 -> mask
        float n0 = __shfl_down(ra.x, 1, 64);
        float n1 = __shfl_down(ra.y, 1, 64);
        float n2 = __shfl_down(ra.z, 1, 64);
        float n3 = __shfl_down(ra.w, 1, 64);
        if (lane == 63) { n0 = n1 = n2 = n3 = 0.f; }  // cols >= 512 -> mask

#define P4(i) ((i) == 0 ? p0 : (i) == 1 ? p1 : (i) == 2 ? p2 : p3)
#define N4(i) ((i) == 0 ? n0 : (i) == 1 ? n1 : (i) == 2 ? n2 : n3)
#pragma unroll
        for (int syi = 0; syi < 9; ++syi) {
#pragma unroll
            for (int k = 0; k < 8; ++k) {
                int i = k + syi;         // window index 0..15 (constant)
                float wv = (i < 4)  ? P4(i)
                         : (i < 8)  ? C4(ra, i - 4)
                         : (i < 12) ? C4(rb, i - 8)
                         :            N4(i - 12);
                float xv = (k < 4) ? C4(xa, k) : C4(xb, k - 4);
                acc[syi] += xv * wv;
            }
        }
#undef P4
#undef N4
    }

    // wave reduce (fp32), block combine in LDS, 9 fp64 atomics per block.
    // Numerics: fp32 block partials summed in fp64 (R2-proven); atomic order
    // nondeterminism ~1e-10 vs inter-sim gaps O(100) -> argmax stable.
    __shared__ float part[4][9];
#pragma unroll
    for (int s = 0; s < 9; ++s) {
        float v = acc[s];
        for (int off = 32; off; off >>= 1) v += __shfl_down(v, off, 64);
        if (lane == 0) part[wave][s] = v;
    }
    __syncthreads();
    if (tid < 9) {
        double tot = (double)part[0][tid] + (double)part[1][tid]
                   + (double)part[2][tid] + (double)part[3][tid];
        atomicAdd(&sims[b * NS + sxi * 9 + tid], tot);
    }
}

// Fused argmax + apply. Each block re-derives its batch's argmax from the
// 81 fp64 sims (L2-resident, 648 B) with first-index tie-break, then shifts
// its 2 rows. One designated block per batch also writes the shift tail.
__global__ __launch_bounds__(256) void k_apply(const float* __restrict__ x,
                                               const double* __restrict__ sims,
                                               float* __restrict__ out,
                                               float* __restrict__ outTail) {
    int blk = blockIdx.x;
    int bc  = blk >> 8;                 // 256 blocks per image (512 rows / 2)
    int tid = threadIdx.x;
    int b   = bc / CC;

    __shared__ double vals[NS];
    __shared__ int bestIdx;
    if (tid < NS) vals[tid] = sims[b * NS + tid];
    __syncthreads();
    if (tid < 64) {
        double v = vals[tid];
        int    i = tid;
        if (tid < NS - 64) {
            double v2 = vals[tid + 64];          // higher index: strict > only
            if (v2 > v) { v = v2; i = tid + 64; }
        }
        for (int off = 32; off; off >>= 1) {
            double ov = __shfl_down(v, off, 64);
            int    oi = __shfl_down(i, off, 64);
            if (ov > v || (ov == v && oi < i)) { v = ov; i = oi; }
        }
        if (tid == 0) bestIdx = i;
    }
    __syncthreads();
    int bi = bestIdx;
    int sx = bi / 9 - 4;
    int sy = bi % 9 - 4;
    if (blk == ((b * CC) << 8) && tid == 0) {    // one block per batch
        outTail[b * 2]     = (float)sx;
        outTail[b * 2 + 1] = (float)sy;
    }

    int row = ((blk & 255) << 1) + (tid >> 7);
    int j0  = (tid & 127) << 2;
    int is  = row - sx;
    float4 v = make_float4(0.f, 0.f, 0.f, 0.f);
    if ((unsigned)is < HH) {
        const float* src = x + (size_t)bc * IMG + is * WW;
        int js0 = j0 - sy;
        if (js0 >= 0 && js0 + 3 < WW) {
            v = *(const float4*)(src + js0);   // 4B-aligned dwordx4, exact (R2-R12)
        } else {
            float* vv = (float*)&v;
#pragma unroll
            for (int k = 0; k < 4; ++k) {
                int js = js0 + k;
                if ((unsigned)js < WW) vv[k] = src[js];
            }
        }
    }
    *(float4*)(out + (size_t)bc * IMG + row * WW + j0) = v;
}

extern "C" void kernel_launch(void* const* d_in, const int* in_sizes, int n_in,
                              void* d_out, int out_size, void* d_ws, size_t ws_size,
                              hipStream_t stream) {
    const float* xref = (const float*)d_in[0];
    const float* x    = (const float*)d_in[1];
    float* out = (float*)d_out;

    double* sims = (double*)d_ws;

    hipMemsetAsync(sims, 0, BB * NS * sizeof(double), stream);

    k_sims<<<NBLK, 256, 0, stream>>>(xref, x, sims);

    int applyBlocks = (BB * CC * HH) / 2;   // 3072
    k_apply<<<applyBlocks, 256, 0, stream>>>(x, sims, out, out + (size_t)BB * CHW);
}